// Round 1
// baseline (12281.133 us; speedup 1.0000x reference)
//
#include <hip/hip_runtime.h>
#include <stdint.h>

// Sizes (fixed per reference): B=128, T=256, N=256, M=256
#define NB 128
#define TTOT 256

typedef _Float16 f16;
typedef _Float16 f16x2 __attribute__((ext_vector_type(2)));

// ---------------- workspace layout (bytes) ----------------
#define WS_PREX   0u            // f16 [128][256][256]  (pre_x[b][n][t'])
#define WS_WUT    16777216u     // u32 [64][256][4]   f16-pairs of WU_e[t'][d], d<512, layout [d8][t'][w]
#define WS_WCAT   17039360u     // u32 [64][1024][4]  f16-pairs of concat(W_ih,W_hh)[j][k], layout [k8][j][w]
#define WS_WXT    18087936u     // f32 [256][256]     WxT[t][t'] = WU_e[t'][512+t]
#define WS_END    18350080u

__device__ __forceinline__ float fast_exp2(float x) {
#if __has_builtin(__builtin_amdgcn_exp2f)
  return __builtin_amdgcn_exp2f(x);
#else
  return exp2f(x);
#endif
}
__device__ __forceinline__ float fast_rcp(float x) {
#if __has_builtin(__builtin_amdgcn_rcpf)
  return __builtin_amdgcn_rcpf(x);
#else
  return 1.0f / x;
#endif
}

// ---------------- K0: pack/transpose weights ----------------
__global__ __launch_bounds__(256) void prep_pack(const float* __restrict__ WU_e,
                                                 const float* __restrict__ W_ih,
                                                 const float* __restrict__ W_hh,
                                                 uint8_t* __restrict__ ws) {
  float* wxt = (float*)(ws + WS_WXT);
  uint32_t* wut = (uint32_t*)(ws + WS_WUT);
  uint32_t* wcat = (uint32_t*)(ws + WS_WCAT);
  int idx = blockIdx.x * blockDim.x + threadIdx.x;
  if (idx < 65536) {
    // WxT[t][t2] = WU_e[t2][512+t]
    int t = idx >> 8, t2 = idx & 255;
    wxt[t * 256 + t2] = WU_e[t2 * 768 + 512 + t];
  } else if (idx < 65536 + 16384) {
    int i = idx - 65536;
    int d8 = i >> 8, tp = i & 255;
    uint32_t* dst = wut + (d8 * 256 + tp) * 4;
#pragma unroll
    for (int w = 0; w < 4; ++w) {
      int d = d8 * 8 + 2 * w;
      f16x2 p;
      p.x = (f16)WU_e[tp * 768 + d];
      p.y = (f16)WU_e[tp * 768 + d + 1];
      dst[w] = __builtin_bit_cast(uint32_t, p);
    }
  } else if (idx < 65536 + 16384 + 65536) {
    int i = idx - (65536 + 16384);
    int k8 = i >> 10, j = i & 1023;
    uint32_t* dst = wcat + (k8 * 1024 + j) * 4;
#pragma unroll
    for (int w = 0; w < 4; ++w) {
      int k0 = k8 * 8 + 2 * w;
      int k1 = k0 + 1;
      float a = (k0 < 256) ? W_ih[j * 256 + k0] : W_hh[j * 256 + (k0 - 256)];
      float b = (k1 < 256) ? W_ih[j * 256 + k1] : W_hh[j * 256 + (k1 - 256)];
      f16x2 p; p.x = (f16)a; p.y = (f16)b;
      dst[w] = __builtin_bit_cast(uint32_t, p);
    }
  }
}

// ---------------- K1: pre_x[b][n][t'] = sum_t X[b][t][n] * WxT[t][t'] ----------------
__global__ __launch_bounds__(512) void prep_prex(const float* __restrict__ X,
                                                 uint8_t* __restrict__ ws) {
  __shared__ float Xs[32][128];
  __shared__ float Wt[32][256];
  const float* wxt = (const float*)(ws + WS_WXT);
  f16* prex = (f16*)(ws + WS_PREX);
  const int b = blockIdx.x >> 1;
  const int n0 = (blockIdx.x & 1) * 128;
  const int tid = threadIdx.x;
  const int tt = tid & 31;      // t' tile: 8 outputs at tt*8
  const int tn = tid >> 5;      // n tile: 8 outputs at tn*8 (tn 0..15)
  float acc[8][8];
#pragma unroll
  for (int i = 0; i < 8; ++i)
#pragma unroll
    for (int j = 0; j < 8; ++j) acc[i][j] = 0.f;

  for (int tc = 0; tc < 8; ++tc) {
#pragma unroll
    for (int it = 0; it < 8; ++it) {
      int idx = tid + it * 512;
      int tr = idx >> 7, nc = idx & 127;
      Xs[tr][nc] = X[((b * 256) + tc * 32 + tr) * 256 + n0 + nc];
    }
#pragma unroll
    for (int it = 0; it < 16; ++it) {
      int idx = tid + it * 512;
      int tr = idx >> 8, c = idx & 255;
      Wt[tr][c] = wxt[(tc * 32 + tr) * 256 + c];
    }
    __syncthreads();
    for (int tr = 0; tr < 32; ++tr) {
      float xa[8], wb[8];
#pragma unroll
      for (int i = 0; i < 8; ++i) xa[i] = Xs[tr][tn * 8 + i];
#pragma unroll
      for (int j = 0; j < 8; ++j) wb[j] = Wt[tr][tt * 8 + j];
#pragma unroll
      for (int i = 0; i < 8; ++i)
#pragma unroll
        for (int j = 0; j < 8; ++j) acc[i][j] = fmaf(xa[i], wb[j], acc[i][j]);
    }
    __syncthreads();
  }
#pragma unroll
  for (int i = 0; i < 8; ++i) {
    int n = n0 + tn * 8 + i;
    uint32_t o[4];
#pragma unroll
    for (int u = 0; u < 4; ++u) {
      f16x2 p; p.x = (f16)acc[i][2 * u]; p.y = (f16)acc[i][2 * u + 1];
      o[u] = __builtin_bit_cast(uint32_t, p);
    }
    *(uint4*)(prex + (size_t)b * 65536 + n * 256 + tt * 8) = make_uint4(o[0], o[1], o[2], o[3]);
  }
}

// ---------------- K2: persistent recurrence, 1 block per batch element ----------------
// LDS layout (bytes):
#define L_PX    0u       // f16, 256 rows, padded stride 528 B (264 f16)
#define L_HS    135168u  // f32[512]: [h(256), c(256)]
#define L_XH    137216u  // f32[512]: [x_tilde(256), h_prev(256)]
#define L_KEH   139264u  // f32[256]: KC * e_pre_h[t']
#define L_WB    140288u  // f32[256]: w = exp(e[n])
#define L_GB    141312u  // f32[1024]: gates
#define L_CB    145408u  // f32[256]: c state
#define L_VE    146432u  // f32[256]: v_e
#define L_BS    147456u  // f32[1024]: b_ih + b_hh
#define LDS_TOTAL 151552u

__global__ __launch_bounds__(1024) void encoder_run(
    const float* __restrict__ X, const float* __restrict__ v_e,
    const float* __restrict__ b_ih, const float* __restrict__ b_hh,
    const uint8_t* __restrict__ ws, float* __restrict__ out) {
  extern __shared__ uint8_t lds[];
  float* hs   = (float*)(lds + L_HS);
  float* xh   = (float*)(lds + L_XH);
  float* keh  = (float*)(lds + L_KEH);
  float* wbuf = (float*)(lds + L_WB);
  float* gbuf = (float*)(lds + L_GB);
  float* cbuf = (float*)(lds + L_CB);
  float* vebuf= (float*)(lds + L_VE);
  float* bsum = (float*)(lds + L_BS);

  const int b = blockIdx.x;
  const int tid = threadIdx.x;
  const uint32_t* wut  = (const uint32_t*)(ws + WS_WUT);
  const uint32_t* wcat = (const uint32_t*)(ws + WS_WCAT);
  const uint32_t* prex_g = (const uint32_t*)(ws + WS_PREX) + (size_t)b * 32768u;

  // ---- init ----
  if (tid < 512) { hs[tid] = 0.f; xh[tid] = 0.f; }
  if (tid < 256) { cbuf[tid] = 0.f; vebuf[tid] = v_e[tid]; }
  bsum[tid] = b_ih[tid] + b_hh[tid];
#pragma unroll
  for (int it = 0; it < 8; ++it) {   // copy pre_x[b] into padded LDS (8192 x 16B)
    int c = tid + it * 1024;
    int row = c >> 5, cc = c & 31;
    uint4 v = *(const uint4*)(prex_g + row * 128 + cc * 4);
    *(uint4*)(lds + row * 528 + cc * 16) = v;
  }
  __syncthreads();

  const float KC = 2.8853900817779268f;  // 2*log2(e)
  const float KL = 1.4426950408889634f;  // log2(e)
  const int tq  = tid & 3;
  const int thi = tid >> 2;   // phase A: t'; phase B: n

  for (int t = 0; t < 256; ++t) {
    // ---- Phase A: e_pre_h[t'] = sum_d hs[d]*WU_e[t'][d], d<512 ----
    {
      float a0 = 0.f, a1 = 0.f, a2 = 0.f, a3 = 0.f;
#pragma unroll
      for (int i = 0; i < 16; ++i) {
        int d8 = tq * 16 + i;
        uint4 wv = *(const uint4*)(wut + (d8 * 256 + thi) * 4);
        float4 h0 = *(const float4*)(hs + d8 * 8);
        float4 h1 = *(const float4*)(hs + d8 * 8 + 4);
        f16x2 p0 = __builtin_bit_cast(f16x2, wv.x);
        f16x2 p1 = __builtin_bit_cast(f16x2, wv.y);
        f16x2 p2 = __builtin_bit_cast(f16x2, wv.z);
        f16x2 p3 = __builtin_bit_cast(f16x2, wv.w);
        a0 = fmaf((float)p0.x, h0.x, a0); a1 = fmaf((float)p0.y, h0.y, a1);
        a2 = fmaf((float)p1.x, h0.z, a2); a3 = fmaf((float)p1.y, h0.w, a3);
        a0 = fmaf((float)p2.x, h1.x, a0); a1 = fmaf((float)p2.y, h1.y, a1);
        a2 = fmaf((float)p3.x, h1.z, a2); a3 = fmaf((float)p3.y, h1.w, a3);
      }
      float a = (a0 + a1) + (a2 + a3);
      a += __shfl_xor(a, 1);
      a += __shfl_xor(a, 2);
      if (tq == 0) keh[thi] = KC * a;
    }
    __syncthreads();

    // ---- Phase B: e[n] = sum_t' ve[t'] * tanh(px + eh), then w=exp(e) ----
    {
      const f16* prow = (const f16*)(lds + thi * 528) + tq * 64;
      float acc = 0.f;
#pragma unroll
      for (int i = 0; i < 8; ++i) {
        uint4 pv = *(const uint4*)(prow + i * 8);
        float4 k0 = *(const float4*)(keh + tq * 64 + i * 8);
        float4 k1 = *(const float4*)(keh + tq * 64 + i * 8 + 4);
        float4 v0 = *(const float4*)(vebuf + tq * 64 + i * 8);
        float4 v1 = *(const float4*)(vebuf + tq * 64 + i * 8 + 4);
        f16x2 q0 = __builtin_bit_cast(f16x2, pv.x);
        f16x2 q1 = __builtin_bit_cast(f16x2, pv.y);
        f16x2 q2 = __builtin_bit_cast(f16x2, pv.z);
        f16x2 q3 = __builtin_bit_cast(f16x2, pv.w);
        float px[8] = {(float)q0.x, (float)q0.y, (float)q1.x, (float)q1.y,
                       (float)q2.x, (float)q2.y, (float)q3.x, (float)q3.y};
        float kv[8] = {k0.x, k0.y, k0.z, k0.w, k1.x, k1.y, k1.z, k1.w};
        float vv[8] = {v0.x, v0.y, v0.z, v0.w, v1.x, v1.y, v1.z, v1.w};
#pragma unroll
        for (int j = 0; j < 8; ++j) {
          float y = fmaf(KC, px[j], kv[j]);          // 2*ln-space arg (log2)
          float u = fast_exp2(y);                    // e^{2x}
          float r = fast_rcp(u + 1.f);
          float th = fmaf(-2.f, r, 1.f);             // tanh(x)
          acc = fmaf(vv[j], th, acc);
        }
      }
      acc += __shfl_xor(acc, 1);
      acc += __shfl_xor(acc, 2);
      if (tq == 0) wbuf[thi] = fast_exp2(KL * acc);  // exp(e[n])
    }
    __syncthreads();

    // ---- Phase C+D: softmax denom (every wave redundantly) + x_tilde ----
    {
      int lane = tid & 63;
      float4 wv = *(const float4*)(wbuf + lane * 4);
      float s = (wv.x + wv.y) + (wv.z + wv.w);
      s += __shfl_xor(s, 1);  s += __shfl_xor(s, 2);  s += __shfl_xor(s, 4);
      s += __shfl_xor(s, 8);  s += __shfl_xor(s, 16); s += __shfl_xor(s, 32);
      float rdenom = fast_rcp(s);
      if (tid < 256) {
        float xv = X[(((size_t)b << 8) + (size_t)t) * 256 + tid];  // X[b][t][n]
        xh[tid] = xv * wbuf[tid] * rdenom;                         // x_tilde[n]
      }
    }
    __syncthreads();

    // ---- Phase E: gates[j] = bsum[j] + sum_k xh[k]*Wcat[j][k] ----
    {
      float a0 = bsum[tid], a1 = 0.f, a2 = 0.f, a3 = 0.f;
#pragma unroll 8
      for (int k8 = 0; k8 < 64; ++k8) {
        uint4 wv = *(const uint4*)(wcat + (k8 * 1024 + tid) * 4);
        float4 x0 = *(const float4*)(xh + k8 * 8);
        float4 x1 = *(const float4*)(xh + k8 * 8 + 4);
        f16x2 p0 = __builtin_bit_cast(f16x2, wv.x);
        f16x2 p1 = __builtin_bit_cast(f16x2, wv.y);
        f16x2 p2 = __builtin_bit_cast(f16x2, wv.z);
        f16x2 p3 = __builtin_bit_cast(f16x2, wv.w);
        a0 = fmaf((float)p0.x, x0.x, a0); a1 = fmaf((float)p0.y, x0.y, a1);
        a2 = fmaf((float)p1.x, x0.z, a2); a3 = fmaf((float)p1.y, x0.w, a3);
        a0 = fmaf((float)p2.x, x1.x, a0); a1 = fmaf((float)p2.y, x1.y, a1);
        a2 = fmaf((float)p3.x, x1.z, a2); a3 = fmaf((float)p3.y, x1.w, a3);
      }
      gbuf[tid] = (a0 + a1) + (a2 + a3);
    }
    __syncthreads();

    // ---- Phase F: LSTM cell update + output ----
    if (tid < 256) {
      float gi = gbuf[tid], gf = gbuf[tid + 256], gg = gbuf[tid + 512], go = gbuf[tid + 768];
      float c_old = cbuf[tid];
      float si = fast_rcp(1.f + fast_exp2(-KL * gi));
      float sf = fast_rcp(1.f + fast_exp2(-KL * gf));
      float so = fast_rcp(1.f + fast_exp2(-KL * go));
      float tg = fmaf(-2.f, fast_rcp(1.f + fast_exp2(KC * gg)), 1.f);
      float cn = fmaf(sf, c_old, si * tg);
      float tc = fmaf(-2.f, fast_rcp(1.f + fast_exp2(KC * cn)), 1.f);
      float hn = so * tc;
      cbuf[tid] = cn;
      hs[tid] = hn; hs[tid + 256] = cn;   // [h, c] for next e_pre_h
      xh[tid + 256] = hn;                 // h part for next gates
      out[(((size_t)t << 7) + (size_t)b) * 256 + tid] = hn;  // out[t][b][m]
    }
    __syncthreads();
  }
}

extern "C" void kernel_launch(void* const* d_in, const int* in_sizes, int n_in,
                              void* d_out, int out_size, void* d_ws, size_t ws_size,
                              hipStream_t stream) {
  const float* X    = (const float*)d_in[0];
  const float* WU_e = (const float*)d_in[1];
  const float* v_e  = (const float*)d_in[2];
  const float* W_ih = (const float*)d_in[3];
  const float* W_hh = (const float*)d_in[4];
  const float* b_ih = (const float*)d_in[5];
  const float* b_hh = (const float*)d_in[6];
  uint8_t* ws = (uint8_t*)d_ws;
  float* out = (float*)d_out;

  (void)hipFuncSetAttribute((const void*)encoder_run,
                            hipFuncAttributeMaxDynamicSharedMemorySize,
                            (int)LDS_TOTAL);

  prep_pack<<<576, 256, 0, stream>>>(WU_e, W_ih, W_hh, ws);
  prep_prex<<<256, 512, 0, stream>>>(X, ws);
  encoder_run<<<NB, 1024, LDS_TOTAL, stream>>>(X, v_e, b_ih, b_hh, ws, out);
}

// Round 2
// 10610.435 us; speedup vs baseline: 1.1575x; 1.1575x over previous
//
#include <hip/hip_runtime.h>
#include <stdint.h>

// Sizes (fixed per reference): B=128, T=256, N=256, M=256
#define NB 128

typedef _Float16 f16;
typedef _Float16 f16x2 __attribute__((ext_vector_type(2)));

// ---------------- workspace layout (bytes) ----------------
#define WS_PREX   0u            // f16 [128][256][256]  (KC * pre_x[b][n][t'])
#define WS_WUT    16777216u     // uint4[16][1024]: chunk for (d8,t') at pos i*1024 + t'*4 + tq, i=d8&15, tq=d8>>4
#define WS_WCAT   17039360u     // uint4[64][1024]: f16-pairs of concat(W_ih,W_hh)[j][k], chunk (k8,j) at k8*1024+j
#define WS_WXT    18087936u     // f32 [256][256]     WxT[t][t'] = WU_e[t'][512+t]
#define WS_END    18350080u

__device__ __forceinline__ float fast_exp2(float x) {
#if __has_builtin(__builtin_amdgcn_exp2f)
  return __builtin_amdgcn_exp2f(x);
#else
  return exp2f(x);
#endif
}
__device__ __forceinline__ float fast_rcp(float x) {
#if __has_builtin(__builtin_amdgcn_rcpf)
  return __builtin_amdgcn_rcpf(x);
#else
  return 1.0f / x;
#endif
}

__device__ __forceinline__ float fdot2(uint32_t w, uint32_t x, float acc) {
#if __has_builtin(__builtin_amdgcn_fdot2)
  return __builtin_amdgcn_fdot2(__builtin_bit_cast(f16x2, w),
                                __builtin_bit_cast(f16x2, x), acc, false);
#else
  f16x2 a = __builtin_bit_cast(f16x2, w);
  f16x2 b = __builtin_bit_cast(f16x2, x);
  acc = fmaf((float)a.x, (float)b.x, acc);
  acc = fmaf((float)a.y, (float)b.y, acc);
  return acc;
#endif
}

__device__ __forceinline__ uint32_t pack2(float lo, float hi) {
#if __has_builtin(__builtin_amdgcn_cvt_pkrtz)
  return __builtin_bit_cast(uint32_t, __builtin_amdgcn_cvt_pkrtz(lo, hi));
#else
  f16x2 p; p.x = (f16)lo; p.y = (f16)hi;
  return __builtin_bit_cast(uint32_t, p);
#endif
}

#define KCONST 2.8853900817779268f  // 2*log2(e)
#define KLOG2E 1.4426950408889634f  // log2(e)

// ---------------- K0: pack/transpose weights ----------------
__global__ __launch_bounds__(256) void prep_pack(const float* __restrict__ WU_e,
                                                 const float* __restrict__ W_ih,
                                                 const float* __restrict__ W_hh,
                                                 uint8_t* __restrict__ ws) {
  float* wxt = (float*)(ws + WS_WXT);
  uint32_t* wut = (uint32_t*)(ws + WS_WUT);
  uint32_t* wcat = (uint32_t*)(ws + WS_WCAT);
  int idx = blockIdx.x * blockDim.x + threadIdx.x;
  if (idx < 65536) {
    // WxT[t][t2] = WU_e[t2][512+t]
    int t = idx >> 8, t2 = idx & 255;
    wxt[t * 256 + t2] = WU_e[t2 * 768 + 512 + t];
  } else if (idx < 65536 + 16384) {
    int i2 = idx - 65536;
    int d8 = i2 >> 8, tp = i2 & 255;
    int ii = d8 & 15, tq = d8 >> 4;
    uint32_t* dst = wut + (ii * 1024 + tp * 4 + tq) * 4;
#pragma unroll
    for (int w = 0; w < 4; ++w) {
      int d = d8 * 8 + 2 * w;
      f16x2 p;
      p.x = (f16)WU_e[tp * 768 + d];
      p.y = (f16)WU_e[tp * 768 + d + 1];
      dst[w] = __builtin_bit_cast(uint32_t, p);
    }
  } else if (idx < 65536 + 16384 + 65536) {
    int i2 = idx - (65536 + 16384);
    int k8 = i2 >> 10, j = i2 & 1023;
    uint32_t* dst = wcat + (k8 * 1024 + j) * 4;
#pragma unroll
    for (int w = 0; w < 4; ++w) {
      int k0 = k8 * 8 + 2 * w;
      int k1 = k0 + 1;
      float a = (k0 < 256) ? W_ih[j * 256 + k0] : W_hh[j * 256 + (k0 - 256)];
      float b = (k1 < 256) ? W_ih[j * 256 + k1] : W_hh[j * 256 + (k1 - 256)];
      f16x2 p; p.x = (f16)a; p.y = (f16)b;
      dst[w] = __builtin_bit_cast(uint32_t, p);
    }
  }
}

// ---------------- K1: pre_x[b][n][t'] = KC * sum_t X[b][t][n] * WxT[t][t'] ----------------
__global__ __launch_bounds__(512) void prep_prex(const float* __restrict__ X,
                                                 uint8_t* __restrict__ ws) {
  __shared__ float Xs[32][128];
  __shared__ float Wt[32][256];
  const float* wxt = (const float*)(ws + WS_WXT);
  f16* prex = (f16*)(ws + WS_PREX);
  const int b = blockIdx.x >> 1;
  const int n0 = (blockIdx.x & 1) * 128;
  const int tid = threadIdx.x;
  const int tt = tid & 31;      // t' tile: 8 outputs at tt*8
  const int tn = tid >> 5;      // n tile: 8 outputs at tn*8 (tn 0..15)
  float acc[8][8];
#pragma unroll
  for (int i = 0; i < 8; ++i)
#pragma unroll
    for (int j = 0; j < 8; ++j) acc[i][j] = 0.f;

  for (int tc = 0; tc < 8; ++tc) {
#pragma unroll
    for (int it = 0; it < 8; ++it) {
      int idx = tid + it * 512;
      int tr = idx >> 7, nc = idx & 127;
      Xs[tr][nc] = X[((b * 256) + tc * 32 + tr) * 256 + n0 + nc];
    }
#pragma unroll
    for (int it = 0; it < 16; ++it) {
      int idx = tid + it * 512;
      int tr = idx >> 8, c = idx & 255;
      Wt[tr][c] = wxt[(tc * 32 + tr) * 256 + c];
    }
    __syncthreads();
    for (int tr = 0; tr < 32; ++tr) {
      float xa[8], wb[8];
#pragma unroll
      for (int i = 0; i < 8; ++i) xa[i] = Xs[tr][tn * 8 + i];
#pragma unroll
      for (int j = 0; j < 8; ++j) wb[j] = Wt[tr][tt * 8 + j];
#pragma unroll
      for (int i = 0; i < 8; ++i)
#pragma unroll
        for (int j = 0; j < 8; ++j) acc[i][j] = fmaf(xa[i], wb[j], acc[i][j]);
    }
    __syncthreads();
  }
#pragma unroll
  for (int i = 0; i < 8; ++i) {
    int n = n0 + tn * 8 + i;
    uint32_t o[4];
#pragma unroll
    for (int u = 0; u < 4; ++u)
      o[u] = pack2(KCONST * acc[i][2 * u], KCONST * acc[i][2 * u + 1]);
    *(uint4*)(prex + (size_t)b * 65536 + n * 256 + tt * 8) = make_uint4(o[0], o[1], o[2], o[3]);
  }
}

// ---------------- K2: persistent recurrence, 1 block per batch element ----------------
// LDS layout (bytes):
#define L_PX    0u       // f16 [256][256] unpadded (512B rows), KC-prescaled
#define L_HSPK  131072u  // u32[256]: f16x2 pairs of [h(128 pairs), c(128 pairs)]
#define L_XHPK  132096u  // u32[256]: f16x2 pairs of [x_tilde(128), h(128)]
#define L_KEH   133120u  // f32[256]: KC * e_pre_h[t']
#define L_WB    134144u  // f32[256]: w = exp(e[n])
#define L_GB    135168u  // f32[1024]: gates
#define LDS_TOTAL 139264u

__global__ __launch_bounds__(1024) void encoder_run(
    const float* __restrict__ X, const float* __restrict__ v_e,
    const float* __restrict__ b_ih, const float* __restrict__ b_hh,
    const uint8_t* __restrict__ ws, float* __restrict__ out) {
  extern __shared__ uint8_t lds[];
  uint32_t* hs_pk = (uint32_t*)(lds + L_HSPK);
  uint32_t* xh_pk = (uint32_t*)(lds + L_XHPK);
  float* keh  = (float*)(lds + L_KEH);
  float* wbuf = (float*)(lds + L_WB);
  float* gbuf = (float*)(lds + L_GB);

  const int b = blockIdx.x;
  const int tid = threadIdx.x;
  const uint4* wut_v  = (const uint4*)(ws + WS_WUT);
  const uint4* wcat_v = (const uint4*)(ws + WS_WCAT);
  const uint32_t* prex_g = (const uint32_t*)(ws + WS_PREX) + (size_t)b * 32768u;

  const int tq  = tid & 3;        // Phase A: K-quarter
  const int thi = tid >> 2;       // Phase A: t'
  const int li  = tid & 31;       // Phase B: 16B chunk within row
  const int half = (tid >> 5) & 1;
  const int wbase = (tid >> 6) * 16;  // Phase B: first row of this wave

  // ---- init ----
  if (tid < 256) { hs_pk[tid] = 0u; xh_pk[tid] = 0u; }
  float creg = 0.f;                       // c state (tid<256)
  float bsum_r = b_ih[tid] + b_hh[tid];   // gate bias (all 1024)
#pragma unroll
  for (int it = 0; it < 8; ++it) {   // copy KC*pre_x[b] into LDS, 8192 x 16B contiguous
    int c = tid + it * 1024;
    uint4 v = *(const uint4*)(prex_g + c * 4);
    *(uint4*)(lds + (size_t)c * 16) = v;
  }
  // Phase-B constants in registers: slices of v_e over this lane's 8 t' values
  float m2ve[8], ve_ssum = 0.f;
  {
    float4 v0 = *(const float4*)(v_e + li * 8);
    float4 v1 = *(const float4*)(v_e + li * 8 + 4);
    float vv[8] = {v0.x, v0.y, v0.z, v0.w, v1.x, v1.y, v1.z, v1.w};
#pragma unroll
    for (int j = 0; j < 8; ++j) { m2ve[j] = -2.f * vv[j]; ve_ssum += vv[j]; }
  }
  __syncthreads();

  for (int t = 0; t < 256; ++t) {
    // ---- top-of-step prefetch issue (T14): wut depth 4, wcat depth 8, X row ----
    uint4 pfa[4], pf[8];
#pragma unroll
    for (int p = 0; p < 4; ++p) pfa[p] = wut_v[p * 1024 + tid];
#pragma unroll
    for (int p = 0; p < 8; ++p) pf[p] = wcat_v[p * 1024 + tid];
    float xv_pre = 0.f;
    if (tid < 256) xv_pre = X[(((size_t)b << 8) + (size_t)t) * 256 + tid];

    // ---- Phase A: keh[t'] = KC * sum_d hs[d]*WU_e[t'][d], d<512 (fdot2) ----
    {
      float a = 0.f;
#pragma unroll
      for (int i = 0; i < 16; ++i) {
        uint4 wv = pfa[i & 3];
        if (i < 12) pfa[i & 3] = wut_v[(i + 4) * 1024 + tid];
        uint4 hv = *(const uint4*)(hs_pk + (tq * 16 + i) * 4);
        a = fdot2(wv.x, hv.x, a);
        a = fdot2(wv.y, hv.y, a);
        a = fdot2(wv.z, hv.z, a);
        a = fdot2(wv.w, hv.w, a);
      }
      a += __shfl_xor(a, 1);
      a += __shfl_xor(a, 2);
      if (tq == 0) keh[thi] = KCONST * a;
    }
    __syncthreads();

    // ---- Phase B: e[n] = sum_t' ve[t']*tanh(px + eh); wbuf[n] = exp(e[n]) ----
    {
      float kr[8];
      {
        float4 k0 = *(const float4*)(keh + li * 8);
        float4 k1 = *(const float4*)(keh + li * 8 + 4);
        kr[0]=k0.x; kr[1]=k0.y; kr[2]=k0.z; kr[3]=k0.w;
        kr[4]=k1.x; kr[5]=k1.y; kr[6]=k1.z; kr[7]=k1.w;
      }
#pragma unroll
      for (int i = 0; i < 8; ++i) {
        int r = wbase + i * 2 + half;
        uint4 pv = *(const uint4*)(lds + (size_t)r * 512 + (size_t)li * 16);
        float acc = ve_ssum;
        uint32_t dw[4] = {pv.x, pv.y, pv.z, pv.w};
#pragma unroll
        for (int u = 0; u < 4; ++u) {
          f16x2 q = __builtin_bit_cast(f16x2, dw[u]);
          {
            float y = (float)q.x + kr[2 * u];
            float e2 = fast_exp2(y);                 // e^{2x} (KC prefolded)
            acc = fmaf(m2ve[2 * u], fast_rcp(e2 + 1.f), acc);
          }
          {
            float y = (float)q.y + kr[2 * u + 1];
            float e2 = fast_exp2(y);
            acc = fmaf(m2ve[2 * u + 1], fast_rcp(e2 + 1.f), acc);
          }
        }
        acc += __shfl_xor(acc, 1);
        acc += __shfl_xor(acc, 2);
        acc += __shfl_xor(acc, 4);
        acc += __shfl_xor(acc, 8);
        acc += __shfl_xor(acc, 16);
        if (li == 0) wbuf[r] = fast_exp2(KLOG2E * acc);
      }
    }
    __syncthreads();

    // ---- Phase C: softmax denom + x_tilde (waves 0-3 only), pack f16 pairs ----
    if (tid < 256) {
      int lane = tid & 63;
      float4 wv = *(const float4*)(wbuf + lane * 4);
      float s = (wv.x + wv.y) + (wv.z + wv.w);
      s += __shfl_xor(s, 1);  s += __shfl_xor(s, 2);  s += __shfl_xor(s, 4);
      s += __shfl_xor(s, 8);  s += __shfl_xor(s, 16); s += __shfl_xor(s, 32);
      float xt = xv_pre * wbuf[tid] * fast_rcp(s);
      float xo = __shfl_xor(xt, 1);
      if (!(tid & 1)) xh_pk[tid >> 1] = pack2(xt, xo);
    }
    __syncthreads();

    // ---- Phase E: gates[j] = bsum[j] + sum_k [x_tilde,h][k]*Wcat[j][k] (fdot2) ----
    {
      float a0 = bsum_r, a1 = 0.f, a2 = 0.f, a3 = 0.f;
#pragma unroll
      for (int k8 = 0; k8 < 64; ++k8) {
        uint4 wv = pf[k8 & 7];
        if (k8 < 56) pf[k8 & 7] = wcat_v[(k8 + 8) * 1024 + tid];
        uint4 xv4 = *(const uint4*)(xh_pk + k8 * 4);
        a0 = fdot2(wv.x, xv4.x, a0);
        a1 = fdot2(wv.y, xv4.y, a1);
        a2 = fdot2(wv.z, xv4.z, a2);
        a3 = fdot2(wv.w, xv4.w, a3);
      }
      gbuf[tid] = (a0 + a1) + (a2 + a3);
    }
    __syncthreads();

    // ---- Phase F: LSTM cell update + output + pack h,c ----
    if (tid < 256) {
      float gi = gbuf[tid], gf = gbuf[tid + 256], gg = gbuf[tid + 512], go = gbuf[tid + 768];
      float si = fast_rcp(1.f + fast_exp2(-KLOG2E * gi));
      float sf = fast_rcp(1.f + fast_exp2(-KLOG2E * gf));
      float so = fast_rcp(1.f + fast_exp2(-KLOG2E * go));
      float tg = fmaf(-2.f, fast_rcp(1.f + fast_exp2(KCONST * gg)), 1.f);
      float cn = fmaf(sf, creg, si * tg);
      float tc2 = fmaf(-2.f, fast_rcp(1.f + fast_exp2(KCONST * cn)), 1.f);
      float hn = so * tc2;
      creg = cn;
      float hp = __shfl_xor(hn, 1);
      float cp = __shfl_xor(cn, 1);
      if (!(tid & 1)) {
        uint32_t hpk = pack2(hn, hp);
        uint32_t cpk = pack2(cn, cp);
        hs_pk[tid >> 1] = hpk;
        hs_pk[128 + (tid >> 1)] = cpk;
        xh_pk[128 + (tid >> 1)] = hpk;
      }
      out[(((size_t)t << 7) + (size_t)b) * 256 + tid] = hn;  // out[t][b][m]
    }
    __syncthreads();
  }
}

extern "C" void kernel_launch(void* const* d_in, const int* in_sizes, int n_in,
                              void* d_out, int out_size, void* d_ws, size_t ws_size,
                              hipStream_t stream) {
  const float* X    = (const float*)d_in[0];
  const float* WU_e = (const float*)d_in[1];
  const float* v_e  = (const float*)d_in[2];
  const float* W_ih = (const float*)d_in[3];
  const float* W_hh = (const float*)d_in[4];
  const float* b_ih = (const float*)d_in[5];
  const float* b_hh = (const float*)d_in[6];
  uint8_t* ws = (uint8_t*)d_ws;
  float* out = (float*)d_out;

  (void)hipFuncSetAttribute((const void*)encoder_run,
                            hipFuncAttributeMaxDynamicSharedMemorySize,
                            (int)LDS_TOTAL);

  prep_pack<<<576, 256, 0, stream>>>(WU_e, W_ih, W_hh, ws);
  prep_prex<<<256, 512, 0, stream>>>(X, ws);
  encoder_run<<<NB, 1024, LDS_TOTAL, stream>>>(X, v_e, b_ih, b_hh, ws, out);
}